// Round 9
// baseline (850.982 us; speedup 1.0000x reference)
//
#include <hip/hip_runtime.h>

// Round 21 (base R20 = 270us): 8 launches -> 3 via producer/consumer flag
// chaining inside ONE "pipeline" kernel (basescan|scan|fill|gather12|conv12
// |gather3 as blockIdx-ranged phases). NOT grid.sync (R17: 150us/sync);
// one-directional agent-scope release/acquire flags + in-order dispatch
// (consumer's producers always resident-or-retired -> no deadlock; spins
// capped). Per-range flags: conv12 tile starts when its 8 gather blocks
// done (overlap); gather3 gated on conv12-seg1 only. conv12 reads W from
// L2 wbuf -> pipeline kernel LDS-free. movie un-aliased from xm_bf (early
// conv writes would race in-flight gathers). conv3_lin = launch 3 (own
// 50KB-LDS kernel). prep_hist zeros flags. Revert path: R20.

typedef unsigned short u16;
typedef unsigned int u32;
typedef __attribute__((ext_vector_type(8))) short bf16x8;
typedef __attribute__((ext_vector_type(4))) float f32x4;

#define NMC 50000
#define NDC 20000
#define EC  600000
#define CM  128
#define CHM ((EC + CM - 1) / CM)   // 4688
#define NWM8 (NMC / 4)             // 12500
#define NWD8 (NDC / 4)             // 5000

// pipeline phase geometry
#define B_P0 274                   // basescan: (70000+255)/256
#define O1 274                     // scan (2 blocks)
#define O2 276                     // fill (4688)
#define O3 4964                    // gather12 (4375)
#define O4 9339                    // conv12 (391+157)
#define O5 9887                    // gather3 (1250)
#define PEND 11137
#define CB1 391                    // (NMC+127)/128
#define CB2 157                    // (NDC+127)/128

// flag slots
#define F_BASE 0
#define F_SCAN 1
#define F_FILL 2
#define F_CONV1 3
#define F_CFLAG 8                  // 548 per-tile counters

__device__ __forceinline__ float bf2f(u16 h) {
    union { u32 u; float f; } v; v.u = ((u32)h) << 16; return v.f;
}
__device__ __forceinline__ float uplo(u32 u) {
    union { u32 u; float f; } t; t.u = u << 16; return t.f;
}
__device__ __forceinline__ float uphi(u32 u) {
    union { u32 u; float f; } t; t.u = u & 0xffff0000u; return t.f;
}
__device__ __forceinline__ u16 f2bf(float f) {
    union { float f; u32 u; } v; v.f = f;
    u32 lsb = (v.u >> 16) & 1u;
    v.u += 0x7fffu + lsb;           // RNE
    return (u16)(v.u >> 16);
}

__device__ __forceinline__ void wait_flag(int* flag, int thresh) {
    if (threadIdx.x == 0) {
        int it = 0;
        while (__hip_atomic_load(flag, __ATOMIC_RELAXED, __HIP_MEMORY_SCOPE_AGENT) < thresh) {
            __builtin_amdgcn_s_sleep(2);
            if (++it > 100000000) break;   // fail gracefully, never hang
        }
        __builtin_amdgcn_fence(__ATOMIC_ACQUIRE, "agent");
    }
    __syncthreads();
}
__device__ __forceinline__ void post_flag(int* flag, int inc) {
    __syncthreads();
    if (threadIdx.x == 0) {
        __builtin_amdgcn_fence(__ATOMIC_RELEASE, "agent");
        __hip_atomic_fetch_add(flag, inc, __ATOMIC_RELAXED, __HIP_MEMORY_SCOPE_AGENT);
    }
}

__device__ __forceinline__ int wave_incl_scan(int v, int lane) {
#pragma unroll
    for (int off = 1; off < 64; off <<= 1) {
        int t = __shfl_up(v, off, 64);
        if (lane >= off) v += t;
    }
    return v;
}

// ------- launch 1: hist | xm/xd->bf16 | wfrag | flag-zero -------
__global__ __launch_bounds__(256)
void prep_hist(const int* __restrict__ dst_m, const int* __restrict__ dst_b,
               int* __restrict__ rank_m, int* __restrict__ rank_b,
               u32* __restrict__ histm, u32* __restrict__ histd,
               const float* __restrict__ xm, u16* __restrict__ xm_bf, int n8m,
               const float* __restrict__ xd, u16* __restrict__ xd_bf, int n8d,
               const float* __restrict__ w0, const float* __restrict__ w1,
               const float* __restrict__ w2, const float* __restrict__ w3,
               const float* __restrict__ w4, const float* __restrict__ w5,
               const float* __restrict__ w6, u16* __restrict__ wbuf,
               int* __restrict__ flags, int TB, int TB2)
{
    __shared__ u32 h[NWM8];         // 50 KB
    const int b = blockIdx.x;
    if (b < 2 * CM) {
        const bool isM = b < CM;
        const int nw = isM ? NWM8 : NWD8;
        for (int i = threadIdx.x; i < nw; i += 256) h[i] = 0;
        __syncthreads();
        if (isM) {
            const int e0 = b * CHM;
            const int e1 = min(EC, e0 + CHM);
            for (int e = e0 + threadIdx.x; e < e1; e += 256) {
                int d = dst_m[e];
                int sh = (d & 3) * 8;
                u32 old = atomicAdd(&h[d >> 2], 1u << sh);
                rank_m[e] = (old >> sh) & 0xffu;
            }
            __syncthreads();
            for (int i = threadIdx.x; i < nw; i += 256)
                histm[(size_t)b * NWM8 + i] = h[i];
        } else {
            const int bb = b - CM;
            const int e0 = bb * CHM;
            const int e1 = min(EC, e0 + CHM);
            for (int e = e0 + threadIdx.x; e < e1; e += 256) {
                int d = dst_b[e];
                int sh = (d & 3) * 8;
                u32 old = atomicAdd(&h[d >> 2], 1u << sh);
                rank_b[e] = (old >> sh) & 0xffu;
            }
            __syncthreads();
            for (int i = threadIdx.x; i < nw; i += 256)
                histd[(size_t)bb * NWD8 + i] = h[i];
        }
        return;
    }
    const int pb = b - 2 * CM;
    if (pb < TB + TB2) {
        const bool isM = pb < TB;
        const float* src = isM ? xm : xd;
        u16* dst = isM ? xm_bf : xd_bf;
        int n8 = isM ? n8m : n8d;
        int i = (pb - (isM ? 0 : TB)) * 256 + threadIdx.x;
        if (i >= n8) return;
        float4 a = ((const float4*)src)[2 * i];
        float4 c2 = ((const float4*)src)[2 * i + 1];
        ushort4 h0; h0.x = f2bf(a.x); h0.y = f2bf(a.y); h0.z = f2bf(a.z); h0.w = f2bf(a.w);
        ushort4 h1; h1.x = f2bf(c2.x); h1.y = f2bf(c2.y); h1.z = f2bf(c2.z); h1.w = f2bf(c2.w);
        ((ushort4*)dst)[2 * i]     = h0;
        ((ushort4*)dst)[2 * i + 1] = h1;
    } else {
        int bb = pb - TB - TB2;
        if (bb >= 448) {            // flag-zero block
            for (int i = threadIdx.x; i < 1024; i += 256) flags[i] = 0;
            return;
        }
        const int widx = bb >> 6;
        const int o    = ((bb & 63) << 8) + threadIdx.x;
        const int OC   = (widx == 6) ? 64 : 128;
        if (o >= OC * 128) return;
        const float* W;
        switch (widx) {
            case 0: W = w0; break; case 1: W = w1; break; case 2: W = w2; break;
            case 3: W = w3; break; case 4: W = w4; break; case 5: W = w5; break;
            default: W = w6;
        }
        int j = o & 7;
        int lane = (o >> 3) & 63;
        int n, c;
        if (OC == 128) { n = (o >> 9) & 7; c = o >> 12; }
        else           { n = (o >> 9) & 3; c = o >> 11; }
        int col = n * 16 + (lane & 15);
        int k   = c * 32 + (lane >> 4) * 8 + j;
        wbuf[widx * 16384 + o] = f2bf(W[k * OC + col]);
    }
}

// ------- launch 2: flag-chained pipeline -------
__global__ __launch_bounds__(256)
void pipeline(u32* __restrict__ histm, u32* __restrict__ histd,
              int* __restrict__ deg_m, int* __restrict__ deg_b,
              int* __restrict__ rp_m, int* __restrict__ rp_b,
              const int* __restrict__ src_m, const int* __restrict__ dst_m,
              const int* __restrict__ src_b, const int* __restrict__ dst_b,
              const float* __restrict__ edge_w,
              const int* __restrict__ rank_m, const int* __restrict__ rank_b,
              int* __restrict__ srcs_m, int2* __restrict__ edges_b,
              const u16* __restrict__ xm_bf, const u16* __restrict__ xd_bf,
              u16* __restrict__ agg1, u16* __restrict__ agg2,
              const u16* __restrict__ wbuf,
              const float* __restrict__ b1, const float* __restrict__ b2,
              u16* __restrict__ movie, u16* __restrict__ t2,
              u16* __restrict__ agg3, int* __restrict__ flags)
{
    const int b   = blockIdx.x;
    const int tid = threadIdx.x;

    if (b < B_P0) {
        // ---- P0: basescan (u8x4, 4 lanes/word x 32 copies) ----
        int t = b * 256 + tid;
        int idx = t >> 2;
        const int q = t & 3;
        u32* hist; int* deg; int NW;
        bool act = true;
        if (idx < NWM8)             { hist = histm; deg = deg_m; NW = NWM8; }
        else if (idx < NWM8 + NWD8) { hist = histd; deg = deg_b; NW = NWD8; idx -= NWM8; }
        else act = false;
        if (act) {
            u32* hp = hist + (size_t)(q * 32) * NW + idx;
            u32 v[32];
#pragma unroll
            for (int j = 0; j < 32; ++j) v[j] = hp[(size_t)j * NW];
            u32 run = 0;
#pragma unroll
            for (int j = 0; j < 32; ++j) { u32 x = v[j]; v[j] = run; run += x; }
            u32 x = run;
            u32 y = __shfl_up(x, 1, 4); if (q >= 1) x += y;
            y = __shfl_up(x, 2, 4);     if (q >= 2) x += y;
            const u32 base = x - run;
#pragma unroll
            for (int j = 0; j < 32; ++j) hp[(size_t)j * NW] = base + v[j];
            if (q == 3) {
                deg[4 * idx + 0] = (int)(x & 0xffu);
                deg[4 * idx + 1] = (int)((x >> 8) & 0xffu);
                deg[4 * idx + 2] = (int)((x >> 16) & 0xffu);
                deg[4 * idx + 3] = (int)(x >> 24);
            }
        }
        post_flag(&flags[F_BASE], 1);
    } else if (b < O2) {
        // ---- P1: exclusive scan + sentinel (256 thr, 32 elems/thr) ----
        wait_flag(&flags[F_BASE], B_P0);
        const bool isM = (b == O1);
        const int* deg = isM ? deg_m : deg_b;
        int* rp = isM ? rp_m : rp_b;
        const int n = isM ? NMC : NDC;
        __shared__ int ws4[4], wx4[4];
        __shared__ int carryS;
        if (tid == 0) carryS = 0;
        __syncthreads();
        const int lane = tid & 63, wid = tid >> 6;
        for (int base = 0; base < n; base += 8192) {
            int idx = base + tid * 32;
            int v[32];
#pragma unroll
            for (int k = 0; k < 8; ++k) {
                int4 qv = make_int4(0, 0, 0, 0);
                int i4 = idx + 4 * k;
                if (i4 + 3 < n) qv = *(const int4*)(deg + i4);
                else {
                    if (i4 + 0 < n) qv.x = deg[i4 + 0];
                    if (i4 + 1 < n) qv.y = deg[i4 + 1];
                    if (i4 + 2 < n) qv.z = deg[i4 + 2];
                    if (i4 + 3 < n) qv.w = deg[i4 + 3];
                }
                v[4 * k] = qv.x; v[4 * k + 1] = qv.y; v[4 * k + 2] = qv.z; v[4 * k + 3] = qv.w;
            }
            int s = 0;
#pragma unroll
            for (int k = 0; k < 32; ++k) s += v[k];
            int incl = wave_incl_scan(s, lane);
            if (lane == 63) ws4[wid] = incl;
            __syncthreads();
            if (tid == 0) { int r = 0; for (int j = 0; j < 4; ++j) { wx4[j] = r; r += ws4[j]; } }
            __syncthreads();
            int c0 = carryS;
            int r = c0 + wx4[wid] + incl - s;
#pragma unroll
            for (int k = 0; k < 32; ++k) { if (idx + k < n) rp[idx + k] = r; r += v[k]; }
            __syncthreads();
            if (tid == 0) carryS = c0 + wx4[3] + ws4[3];
            __syncthreads();
        }
        if (tid == 0) rp[n] = carryS;
        post_flag(&flags[F_SCAN], 1);
    } else if (b < O3) {
        // ---- P2: fill ----
        wait_flag(&flags[F_SCAN], 2);
        int t = (b - O2) * 256 + tid;
        if (t < EC) {
            int d = dst_m[t];
            int c = t / CHM;
            u32 pk = histm[(size_t)c * NWM8 + (d >> 2)];
            int base = (pk >> ((d & 3) * 8)) & 0xffu;
            int pos = rp_m[d] + base + rank_m[t];
            srcs_m[pos] = src_m[t];
        } else if (t < 2 * EC) {
            int e = t - EC;
            int d = dst_b[e];
            int c = e / CHM;
            u32 pkb = histd[(size_t)c * NWD8 + (d >> 2)];
            int base = (pkb >> ((d & 3) * 8)) & 0xffu;
            int pos = rp_b[d] + base + rank_b[e];
            float x = edge_w[e];
            int2 pk;
            pk.x = src_b[e];
            pk.y = __float_as_int(1.0f / (1.0f + __expf(-x)));
            edges_b[pos] = pk;
        }
        post_flag(&flags[F_FILL], 1);
    } else if (b < O4) {
        // ---- P3: gather12 (16-lane groups, 16B loads) ----
        wait_flag(&flags[F_FILL], 4688);
        const int g  = b - O3;
        const int h  = g * 16 + (tid >> 4);
        const int cl = tid & 15;
        float a0 = 0.f, a1 = 0.f, a2 = 0.f, a3 = 0.f;
        float a4 = 0.f, a5 = 0.f, a6 = 0.f, a7 = 0.f;
        if (h < NMC) {
            int i = rp_m[h], end = rp_m[h + 1];
            for (; i + 8 <= end; i += 8) {
                int s[8];
#pragma unroll
                for (int k = 0; k < 8; ++k) s[k] = srcs_m[i + k];
                uint4 v[8];
#pragma unroll
                for (int k = 0; k < 8; ++k)
                    v[k] = *(const uint4*)(xm_bf + (size_t)s[k] * 128 + cl * 8);
#pragma unroll
                for (int k = 0; k < 8; ++k) {
                    a0 += uplo(v[k].x); a1 += uphi(v[k].x);
                    a2 += uplo(v[k].y); a3 += uphi(v[k].y);
                    a4 += uplo(v[k].z); a5 += uphi(v[k].z);
                    a6 += uplo(v[k].w); a7 += uphi(v[k].w);
                }
            }
            for (; i < end; ++i) {
                uint4 v = *(const uint4*)(xm_bf + (size_t)srcs_m[i] * 128 + cl * 8);
                a0 += uplo(v.x); a1 += uphi(v.x);
                a2 += uplo(v.y); a3 += uphi(v.y);
                a4 += uplo(v.z); a5 += uphi(v.z);
                a6 += uplo(v.w); a7 += uphi(v.w);
            }
            uint4 st;
            st.x = (u32)f2bf(a0) | ((u32)f2bf(a1) << 16);
            st.y = (u32)f2bf(a2) | ((u32)f2bf(a3) << 16);
            st.z = (u32)f2bf(a4) | ((u32)f2bf(a5) << 16);
            st.w = (u32)f2bf(a6) | ((u32)f2bf(a7) << 16);
            *(uint4*)(agg1 + (size_t)h * 128 + cl * 8) = st;
        } else {
            int node = h - NMC;
            int i = rp_b[node], end = rp_b[node + 1];
            for (; i + 8 <= end; i += 8) {
                int2 p[8];
#pragma unroll
                for (int k = 0; k < 8; ++k) p[k] = edges_b[i + k];
                uint4 v[8];
#pragma unroll
                for (int k = 0; k < 8; ++k)
                    v[k] = *(const uint4*)(xm_bf + (size_t)p[k].x * 128 + cl * 8);
#pragma unroll
                for (int k = 0; k < 8; ++k) {
                    float w = __int_as_float(p[k].y);
                    a0 = fmaf(w, uplo(v[k].x), a0); a1 = fmaf(w, uphi(v[k].x), a1);
                    a2 = fmaf(w, uplo(v[k].y), a2); a3 = fmaf(w, uphi(v[k].y), a3);
                    a4 = fmaf(w, uplo(v[k].z), a4); a5 = fmaf(w, uphi(v[k].z), a5);
                    a6 = fmaf(w, uplo(v[k].w), a6); a7 = fmaf(w, uphi(v[k].w), a7);
                }
            }
            for (; i < end; ++i) {
                int2 pk = edges_b[i];
                float w = __int_as_float(pk.y);
                uint4 v = *(const uint4*)(xm_bf + (size_t)pk.x * 128 + cl * 8);
                a0 = fmaf(w, uplo(v.x), a0); a1 = fmaf(w, uphi(v.x), a1);
                a2 = fmaf(w, uplo(v.y), a2); a3 = fmaf(w, uphi(v.y), a3);
                a4 = fmaf(w, uplo(v.z), a4); a5 = fmaf(w, uphi(v.z), a5);
                a6 = fmaf(w, uplo(v.w), a6); a7 = fmaf(w, uphi(v.w), a7);
            }
            uint4 st;
            st.x = (u32)f2bf(a0) | ((u32)f2bf(a1) << 16);
            st.y = (u32)f2bf(a2) | ((u32)f2bf(a3) << 16);
            st.z = (u32)f2bf(a4) | ((u32)f2bf(a5) << 16);
            st.w = (u32)f2bf(a6) | ((u32)f2bf(a7) << 16);
            *(uint4*)(agg2 + (size_t)node * 128 + cl * 8) = st;
        }
        const int cidx = (g < 3125) ? (g >> 3) : (CB1 + ((g - 3125) >> 3));
        post_flag(&flags[F_CFLAG + cidx], 1);
    } else if (b < O5) {
        // ---- P4: conv12 (W from global wbuf, no LDS) ----
        const int b4 = b - O4;
        const bool seg1 = b4 < CB1;
        const int base = seg1 ? b4 : (b4 - CB1);
        const int thr = seg1 ? min(8, 3125 - 8 * base) : min(8, 1250 - 8 * base);
        wait_flag(&flags[F_CFLAG + (seg1 ? base : CB1 + base)], thr);

        const u16* A0 = seg1 ? agg1 : agg2;
        const u16* Ar = seg1 ? xm_bf : xd_bf;
        const u16* Wr = wbuf + (seg1 ? 0 : 2) * 16384;
        const u16* Wo = wbuf + (seg1 ? 1 : 3) * 16384;
        const float* bias = seg1 ? b1 : b2;
        u16* C = seg1 ? movie : t2;
        const int N = seg1 ? NMC : NDC;

        const int lane = tid & 63;
        const int m0   = (base * 4 + (tid >> 6)) * 32;
        const int lr   = lane & 15;
        const int quad = lane >> 4;
        int r0 = m0 + lr;      if (r0 >= N) r0 = N - 1;
        int r1 = m0 + 16 + lr; if (r1 >= N) r1 = N - 1;

        f32x4 acc[2][8];
#pragma unroll
        for (int mt = 0; mt < 2; ++mt)
#pragma unroll
            for (int n = 0; n < 8; ++n) acc[mt][n] = (f32x4){0.f, 0.f, 0.f, 0.f};

#pragma unroll
        for (int c = 0; c < 4; ++c) {
            const int kb = c * 32 + quad * 8;
            bf16x8 a0v = *(const bf16x8*)(A0 + (size_t)r0 * 128 + kb);
            bf16x8 a1v = *(const bf16x8*)(A0 + (size_t)r1 * 128 + kb);
            const u16* wp = Wr + c * 4096 + lane * 8;
#pragma unroll
            for (int n = 0; n < 8; ++n) {
                bf16x8 bv = *(const bf16x8*)(wp + n * 512);
                acc[0][n] = __builtin_amdgcn_mfma_f32_16x16x32_bf16(a0v, bv, acc[0][n], 0, 0, 0);
                acc[1][n] = __builtin_amdgcn_mfma_f32_16x16x32_bf16(a1v, bv, acc[1][n], 0, 0, 0);
            }
        }
#pragma unroll
        for (int c = 0; c < 4; ++c) {
            const int kb = c * 32 + quad * 8;
            bf16x8 a0v = *(const bf16x8*)(Ar + (size_t)r0 * 128 + kb);
            bf16x8 a1v = *(const bf16x8*)(Ar + (size_t)r1 * 128 + kb);
            const u16* wp = Wo + c * 4096 + lane * 8;
#pragma unroll
            for (int n = 0; n < 8; ++n) {
                bf16x8 bv = *(const bf16x8*)(wp + n * 512);
                acc[0][n] = __builtin_amdgcn_mfma_f32_16x16x32_bf16(a0v, bv, acc[0][n], 0, 0, 0);
                acc[1][n] = __builtin_amdgcn_mfma_f32_16x16x32_bf16(a1v, bv, acc[1][n], 0, 0, 0);
            }
        }
#pragma unroll
        for (int mt = 0; mt < 2; ++mt) {
#pragma unroll
            for (int n = 0; n < 8; ++n) {
                const int col = n * 16 + lr;
                const float bb = bias[col];
#pragma unroll
                for (int r = 0; r < 4; ++r) {
                    int row = m0 + mt * 16 + quad * 4 + r;
                    if (row >= N) continue;
                    C[(size_t)row * 128 + col] = f2bf(fmaxf(acc[mt][n][r] + bb, 0.f));
                }
            }
        }
        if (seg1) post_flag(&flags[F_CONV1], 1);
    } else {
        // ---- P5: gather3 (weighted, from movie) ----
        wait_flag(&flags[F_CONV1], CB1);
        const int g = b - O5;
        const int node = g * 16 + (tid >> 4);
        const int cl = tid & 15;
        int i = rp_b[node], end = rp_b[node + 1];
        float a0 = 0.f, a1 = 0.f, a2 = 0.f, a3 = 0.f;
        float a4 = 0.f, a5 = 0.f, a6 = 0.f, a7 = 0.f;
        for (; i + 8 <= end; i += 8) {
            int2 p[8];
#pragma unroll
            for (int k = 0; k < 8; ++k) p[k] = edges_b[i + k];
            uint4 v[8];
#pragma unroll
            for (int k = 0; k < 8; ++k)
                v[k] = *(const uint4*)(movie + (size_t)p[k].x * 128 + cl * 8);
#pragma unroll
            for (int k = 0; k < 8; ++k) {
                float w = __int_as_float(p[k].y);
                a0 = fmaf(w, uplo(v[k].x), a0); a1 = fmaf(w, uphi(v[k].x), a1);
                a2 = fmaf(w, uplo(v[k].y), a2); a3 = fmaf(w, uphi(v[k].y), a3);
                a4 = fmaf(w, uplo(v[k].z), a4); a5 = fmaf(w, uphi(v[k].z), a5);
                a6 = fmaf(w, uplo(v[k].w), a6); a7 = fmaf(w, uphi(v[k].w), a7);
            }
        }
        for (; i < end; ++i) {
            int2 pk = edges_b[i];
            float w = __int_as_float(pk.y);
            uint4 v = *(const uint4*)(movie + (size_t)pk.x * 128 + cl * 8);
            a0 = fmaf(w, uplo(v.x), a0); a1 = fmaf(w, uphi(v.x), a1);
            a2 = fmaf(w, uplo(v.y), a2); a3 = fmaf(w, uphi(v.y), a3);
            a4 = fmaf(w, uplo(v.z), a4); a5 = fmaf(w, uphi(v.z), a5);
            a6 = fmaf(w, uplo(v.w), a6); a7 = fmaf(w, uphi(v.w), a7);
        }
        uint4 st;
        st.x = (u32)f2bf(a0) | ((u32)f2bf(a1) << 16);
        st.y = (u32)f2bf(a2) | ((u32)f2bf(a3) << 16);
        st.z = (u32)f2bf(a4) | ((u32)f2bf(a5) << 16);
        st.w = (u32)f2bf(a6) | ((u32)f2bf(a7) << 16);
        *(uint4*)(agg3 + (size_t)node * 128 + cl * 8) = st;
    }
}

// ------- launch 3: conv3 + lin fused (bf16 A), 50 KB LDS -------
__global__ __launch_bounds__(256)
void conv3_lin(const u16* __restrict__ A1, const u16* __restrict__ Wr,
               const float* __restrict__ bias3,
               const u16* __restrict__ A2, const u16* __restrict__ Wo,
               const u16* __restrict__ Wl, const float* __restrict__ bias_l,
               float* __restrict__ out, int N)
{
    __shared__ u16 lds[17408 + 8192];
    u16* tile = lds;
    u16* sWl  = lds + 17408;

    const int tid  = threadIdx.x;
    const int lane = tid & 63;
    const int wv   = tid >> 6;
    const int wbase = wv * 32;
    const int m0   = (blockIdx.x * 4 + wv) * 32;
    const int lr   = lane & 15;
    const int quad = lane >> 4;

    int r0 = m0 + lr;      if (r0 >= N) r0 = N - 1;
    int r1 = m0 + 16 + lr; if (r1 >= N) r1 = N - 1;

    f32x4 acc[2][8];
#pragma unroll
    for (int mt = 0; mt < 2; ++mt)
#pragma unroll
        for (int n = 0; n < 8; ++n) acc[mt][n] = (f32x4){0.f, 0.f, 0.f, 0.f};

    for (int i = tid; i < 1024; i += 256)
        ((uint4*)sWl)[i] = ((const uint4*)Wl)[i];
    for (int i = tid; i < 2048; i += 256)
        ((uint4*)lds)[i] = ((const uint4*)Wr)[i];
    __syncthreads();
#pragma unroll
    for (int c = 0; c < 4; ++c) {
        const int kb = c * 32 + quad * 8;
        bf16x8 a0 = *(const bf16x8*)(A1 + (size_t)r0 * 128 + kb);
        bf16x8 a1 = *(const bf16x8*)(A1 + (size_t)r1 * 128 + kb);
        const u16* wp = lds + c * 4096 + lane * 8;
#pragma unroll
        for (int n = 0; n < 8; ++n) {
            bf16x8 b = *(const bf16x8*)(wp + n * 512);
            acc[0][n] = __builtin_amdgcn_mfma_f32_16x16x32_bf16(a0, b, acc[0][n], 0, 0, 0);
            acc[1][n] = __builtin_amdgcn_mfma_f32_16x16x32_bf16(a1, b, acc[1][n], 0, 0, 0);
        }
    }
    __syncthreads();
    for (int i = tid; i < 2048; i += 256)
        ((uint4*)lds)[i] = ((const uint4*)Wo)[i];
    __syncthreads();
#pragma unroll
    for (int c = 0; c < 4; ++c) {
        const int kb = c * 32 + quad * 8;
        bf16x8 a0 = *(const bf16x8*)(A2 + (size_t)r0 * 128 + kb);
        bf16x8 a1 = *(const bf16x8*)(A2 + (size_t)r1 * 128 + kb);
        const u16* wp = lds + c * 4096 + lane * 8;
#pragma unroll
        for (int n = 0; n < 8; ++n) {
            bf16x8 b = *(const bf16x8*)(wp + n * 512);
            acc[0][n] = __builtin_amdgcn_mfma_f32_16x16x32_bf16(a0, b, acc[0][n], 0, 0, 0);
            acc[1][n] = __builtin_amdgcn_mfma_f32_16x16x32_bf16(a1, b, acc[1][n], 0, 0, 0);
        }
    }
    __syncthreads();

#pragma unroll
    for (int mt = 0; mt < 2; ++mt) {
#pragma unroll
        for (int n = 0; n < 8; ++n) {
            const int col = n * 16 + lr;
            const float b = bias3[col];
#pragma unroll
            for (int r = 0; r < 4; ++r) {
                int row = wbase + mt * 16 + quad * 4 + r;
                tile[row * 136 + col] = f2bf(fmaxf(acc[mt][n][r] + b, 0.f));
            }
        }
    }
    __syncthreads();

    f32x4 acc2[2][4];
#pragma unroll
    for (int mt = 0; mt < 2; ++mt)
#pragma unroll
        for (int n = 0; n < 4; ++n) acc2[mt][n] = (f32x4){0.f, 0.f, 0.f, 0.f};

#pragma unroll
    for (int c = 0; c < 4; ++c) {
        const int kb = c * 32 + quad * 8;
        bf16x8 a0 = *(const bf16x8*)(tile + (wbase + lr) * 136 + kb);
        bf16x8 a1 = *(const bf16x8*)(tile + (wbase + 16 + lr) * 136 + kb);
#pragma unroll
        for (int n = 0; n < 4; ++n) {
            bf16x8 b = *(const bf16x8*)(sWl + c * 2048 + n * 512 + lane * 8);
            acc2[0][n] = __builtin_amdgcn_mfma_f32_16x16x32_bf16(a0, b, acc2[0][n], 0, 0, 0);
            acc2[1][n] = __builtin_amdgcn_mfma_f32_16x16x32_bf16(a1, b, acc2[1][n], 0, 0, 0);
        }
    }

#pragma unroll
    for (int mt = 0; mt < 2; ++mt) {
#pragma unroll
        for (int n = 0; n < 4; ++n) {
            const int col = n * 16 + lr;
            const float b = bias_l[col];
#pragma unroll
            for (int r = 0; r < 4; ++r) {
                int row = m0 + mt * 16 + quad * 4 + r;
                if (row >= N) continue;
                out[(size_t)row * 64 + col] = acc2[mt][n][r] + b;
            }
        }
    }
}

extern "C" void kernel_launch(void* const* d_in, const int* in_sizes, int n_in,
                              void* d_out, int out_size, void* d_ws, size_t ws_size,
                              hipStream_t stream)
{
    const float* x_meas  = (const float*)d_in[0];
    const float* x_dem   = (const float*)d_in[1];
    const int*   src_m   = (const int*)d_in[2];
    const int*   dst_m   = (const int*)d_in[3];
    const int*   src_b   = (const int*)d_in[4];
    const int*   dst_b   = (const int*)d_in[5];
    const float* edge_w  = (const float*)d_in[6];
    const float* W_rel1  = (const float*)d_in[7];
    const float* b_rel1  = (const float*)d_in[8];
    const float* W_root1 = (const float*)d_in[9];
    const float* W_rel2  = (const float*)d_in[10];
    const float* b_rel2  = (const float*)d_in[11];
    const float* W_root2 = (const float*)d_in[12];
    const float* W_rel3  = (const float*)d_in[13];
    const float* b_rel3  = (const float*)d_in[14];
    const float* W_root3 = (const float*)d_in[15];
    const float* W_lin   = (const float*)d_in[16];
    const float* b_lin   = (const float*)d_in[17];
    float* out = (float*)d_out;

    const int NM = NMC, ND = NDC;

    char* p = (char*)d_ws;
    auto alloc = [&](size_t bytes) { char* r = p; p += (bytes + 511) & ~(size_t)511; return r; };
    u32*   histm   = (u32*)alloc((size_t)CM * NWM8 * 4);  // 6.4 MB
    u32*   histd   = (u32*)alloc((size_t)CM * NWD8 * 4);  // 2.56 MB
    int*   deg_m   = (int*)alloc((size_t)NM * 4);
    int*   deg_b   = (int*)alloc((size_t)ND * 4);
    int*   rp_m    = (int*)alloc((size_t)(NM + 1) * 4);
    int*   rp_b    = (int*)alloc((size_t)(ND + 1) * 4);
    int*   srcs_m  = (int*)alloc((size_t)EC * 4);
    int2*  edges_b = (int2*)alloc((size_t)EC * 8);
    u16*   xm_bf   = (u16*)alloc((size_t)NM * 128 * 2);   // 12.8 MB (pristine)
    u16*   movie   = (u16*)alloc((size_t)NM * 128 * 2);   // 12.8 MB conv1 out
    u16*   agg1    = (u16*)alloc((size_t)NM * 128 * 2);   // 12.8 MB
    u16*   agg2    = (u16*)alloc((size_t)ND * 128 * 2);   // 5.12 MB
    u16*   xd_bf   = (u16*)alloc((size_t)ND * 128 * 2);   // 5.12 MB
    u16*   t2      = (u16*)alloc((size_t)ND * 128 * 2);   // 5.12 MB
    u16*   wbuf    = (u16*)alloc(7 * 16384 * 2);          // 224 KB
    int*   flags   = (int*)alloc(1024 * 4);
    // aliases (flag-ordered lifetimes):
    int* rank_m = (int*)agg1;          // read in P2; agg1 written in P3
    int* rank_b = rank_m + EC;
    u16* agg3   = agg1;                // agg1 dead after conv12 seg1 (P5 gated)

    const int TB  = (NM * 16 + 255) / 256;     // 3125
    const int TB2 = (ND * 16 + 255) / 256;     // 1250
    const int WB  = 448;

    prep_hist<<<2 * CM + TB + TB2 + WB + 1, 256, 0, stream>>>(
        dst_m, dst_b, rank_m, rank_b, histm, histd,
        x_meas, xm_bf, NM * 16, x_dem, xd_bf, ND * 16,
        W_rel1, W_root1, W_rel2, W_root2, W_rel3, W_root3, W_lin, wbuf,
        flags, TB, TB2);

    pipeline<<<PEND, 256, 0, stream>>>(
        histm, histd, deg_m, deg_b, rp_m, rp_b,
        src_m, dst_m, src_b, dst_b, edge_w, rank_m, rank_b,
        srcs_m, edges_b, xm_bf, xd_bf, agg1, agg2, wbuf,
        b_rel1, b_rel2, movie, t2, agg3, flags);

    u16* w3r = wbuf + 4 * 16384; u16* w3o = wbuf + 5 * 16384;
    u16* wl  = wbuf + 6 * 16384;
    conv3_lin<<<CB2, 256, 0, stream>>>(agg3, w3r, b_rel3, t2, w3o, wl, b_lin, out, ND);
}

// Round 10
// 266.085 us; speedup vs baseline: 3.1982x; 3.1982x over previous
//
#include <hip/hip_runtime.h>

// Round 22 (base R20 = 270us; R21 flag-pipeline catastrophically slow --
// spin-polling saturates coherence fabric, occupancy union-VGPR-crushed;
// lesson: kernel boundaries ARE the cheap sync on gfx950).
// R20 + three safe refinements:
// (1) conv12_mfma LDS-free: W frags straight from L2 wbuf (body verified
//     correct by R21's passing run) -- no barriers, no 32KB LDS.
// (2) gathers reverted to 32-lane 8-deep (R19: 44.0us vs R20 16-lane 46.0).
// (3) fill: int4-vectorized edge reads, 4 edges/thread (grid 4688->1172).
// prep_hist(u8)/basescan8/scan2 unchanged from R20.

typedef unsigned short u16;
typedef unsigned int u32;
typedef __attribute__((ext_vector_type(8))) short bf16x8;
typedef __attribute__((ext_vector_type(4))) float f32x4;

#define NMC 50000
#define NDC 20000
#define EC  600000
#define CM  128                    // histogram copies (both graphs)
#define CHM ((EC + CM - 1) / CM)   // 4688
#define NWM8 (NMC / 4)             // 12500 packed u8x4 words
#define NWD8 (NDC / 4)             // 5000

__device__ __forceinline__ float bf2f(u16 h) {
    union { u32 u; float f; } v; v.u = ((u32)h) << 16; return v.f;
}
__device__ __forceinline__ u16 f2bf(float f) {
    union { float f; u32 u; } v; v.f = f;
    u32 lsb = (v.u >> 16) & 1u;
    v.u += 0x7fffu + lsb;           // RNE
    return (u16)(v.u >> 16);
}

// ------- merged: LDS u8-histogram (blocks 0..255) | prep (rest) -------
__global__ __launch_bounds__(256)
void prep_hist(const int* __restrict__ dst_m, const int* __restrict__ dst_b,
               int* __restrict__ rank_m, int* __restrict__ rank_b,
               u32* __restrict__ histm, u32* __restrict__ histd,
               const float* __restrict__ xm, u16* __restrict__ xm_bf, int n8m,
               const float* __restrict__ xd, u16* __restrict__ xd_bf, int n8d,
               const float* __restrict__ w0, const float* __restrict__ w1,
               const float* __restrict__ w2, const float* __restrict__ w3,
               const float* __restrict__ w4, const float* __restrict__ w5,
               const float* __restrict__ w6, u16* __restrict__ wbuf,
               int TB, int TB2)
{
    __shared__ u32 h[NWM8];         // 50 KB; dem blocks use first NWD8
    const int b = blockIdx.x;
    if (b < 2 * CM) {
        const bool isM = b < CM;
        const int nw = isM ? NWM8 : NWD8;
        for (int i = threadIdx.x; i < nw; i += 256) h[i] = 0;
        __syncthreads();
        if (isM) {
            const int e0 = b * CHM;
            const int e1 = min(EC, e0 + CHM);
            for (int e = e0 + threadIdx.x; e < e1; e += 256) {
                int d = dst_m[e];
                int sh = (d & 3) * 8;
                u32 old = atomicAdd(&h[d >> 2], 1u << sh);
                rank_m[e] = (old >> sh) & 0xffu;
            }
            __syncthreads();
            for (int i = threadIdx.x; i < nw; i += 256)
                histm[(size_t)b * NWM8 + i] = h[i];
        } else {
            const int bb = b - CM;
            const int e0 = bb * CHM;
            const int e1 = min(EC, e0 + CHM);
            for (int e = e0 + threadIdx.x; e < e1; e += 256) {
                int d = dst_b[e];
                int sh = (d & 3) * 8;
                u32 old = atomicAdd(&h[d >> 2], 1u << sh);
                rank_b[e] = (old >> sh) & 0xffu;
            }
            __syncthreads();
            for (int i = threadIdx.x; i < nw; i += 256)
                histd[(size_t)bb * NWD8 + i] = h[i];
        }
        return;
    }
    const int pb = b - 2 * CM;
    if (pb < TB + TB2) {
        const bool isM = pb < TB;
        const float* src = isM ? xm : xd;
        u16* dst = isM ? xm_bf : xd_bf;
        int n8 = isM ? n8m : n8d;
        int i = (pb - (isM ? 0 : TB)) * 256 + threadIdx.x;
        if (i >= n8) return;
        float4 a = ((const float4*)src)[2 * i];
        float4 c2 = ((const float4*)src)[2 * i + 1];
        ushort4 h0; h0.x = f2bf(a.x); h0.y = f2bf(a.y); h0.z = f2bf(a.z); h0.w = f2bf(a.w);
        ushort4 h1; h1.x = f2bf(c2.x); h1.y = f2bf(c2.y); h1.z = f2bf(c2.z); h1.w = f2bf(c2.w);
        ((ushort4*)dst)[2 * i]     = h0;
        ((ushort4*)dst)[2 * i + 1] = h1;
    } else {
        int bb = pb - TB - TB2;
        const int widx = bb >> 6;
        const int o    = ((bb & 63) << 8) + threadIdx.x;
        const int OC   = (widx == 6) ? 64 : 128;
        if (o >= OC * 128) return;
        const float* W;
        switch (widx) {
            case 0: W = w0; break; case 1: W = w1; break; case 2: W = w2; break;
            case 3: W = w3; break; case 4: W = w4; break; case 5: W = w5; break;
            default: W = w6;
        }
        int j = o & 7;
        int lane = (o >> 3) & 63;
        int n, c;
        if (OC == 128) { n = (o >> 9) & 7; c = o >> 12; }
        else           { n = (o >> 9) & 3; c = o >> 11; }
        int col = n * 16 + (lane & 15);
        int k   = c * 32 + (lane >> 4) * 8 + j;
        wbuf[widx * 16384 + o] = f2bf(W[k * OC + col]);
    }
}

// ------- per-node scan over copies, u8x4-packed (4 lanes x 32 copies) -------
__global__ __launch_bounds__(256)
void basescan8(u32* __restrict__ histm, u32* __restrict__ histd,
               int* __restrict__ deg_m, int* __restrict__ deg_b)
{
    int t = blockIdx.x * 256 + threadIdx.x;
    int idx = t >> 2;
    const int q = t & 3;
    u32* hist; int* deg; int NW;
    if (idx < NWM8)             { hist = histm; deg = deg_m; NW = NWM8; }
    else if (idx < NWM8 + NWD8) { hist = histd; deg = deg_b; NW = NWD8; idx -= NWM8; }
    else return;

    u32* hp = hist + (size_t)(q * 32) * NW + idx;
    u32 v[32];
#pragma unroll
    for (int j = 0; j < 32; ++j) v[j] = hp[(size_t)j * NW];
    u32 run = 0;                // packed u8x4; per-byte totals <= deg < 256
#pragma unroll
    for (int j = 0; j < 32; ++j) { u32 x = v[j]; v[j] = run; run += x; }
    u32 x = run;
    u32 y = __shfl_up(x, 1, 4); if (q >= 1) x += y;
    y = __shfl_up(x, 2, 4);     if (q >= 2) x += y;
    const u32 base = x - run;
#pragma unroll
    for (int j = 0; j < 32; ++j) hp[(size_t)j * NW] = base + v[j];
    if (q == 3) {
        deg[4 * idx + 0] = (int)(x & 0xffu);
        deg[4 * idx + 1] = (int)((x >> 8) & 0xffu);
        deg[4 * idx + 2] = (int)((x >> 16) & 0xffu);
        deg[4 * idx + 3] = (int)(x >> 24);
    }
}

__device__ __forceinline__ int wave_incl_scan(int v, int lane) {
#pragma unroll
    for (int off = 1; off < 64; off <<= 1) {
        int t = __shfl_up(v, off, 64);
        if (lane >= off) v += t;
    }
    return v;
}

// exclusive scan + sentinel, 8 elems/thread
__global__ __launch_bounds__(1024)
void scan2_kernel(const int* __restrict__ degA, int* __restrict__ rpA, int nA,
                  const int* __restrict__ degB, int* __restrict__ rpB, int nB)
{
    const int* deg = blockIdx.x ? degB : degA;
    int* rp = blockIdx.x ? rpB : rpA;
    int n = blockIdx.x ? nB : nA;

    __shared__ int wsum[16];
    __shared__ int carry;
    const int tid = threadIdx.x, lane = tid & 63, wid = tid >> 6;
    if (tid == 0) carry = 0;
    __syncthreads();

    for (int base = 0; base < n; base += 8192) {
        int idx = base + tid * 8;
        int4 va = make_int4(0, 0, 0, 0), vb = make_int4(0, 0, 0, 0);
        if (idx + 7 < n) {
            va = *(const int4*)(deg + idx);
            vb = *(const int4*)(deg + idx + 4);
        } else {
            if (idx + 0 < n) va.x = deg[idx + 0];
            if (idx + 1 < n) va.y = deg[idx + 1];
            if (idx + 2 < n) va.z = deg[idx + 2];
            if (idx + 3 < n) va.w = deg[idx + 3];
            if (idx + 4 < n) vb.x = deg[idx + 4];
            if (idx + 5 < n) vb.y = deg[idx + 5];
            if (idx + 6 < n) vb.z = deg[idx + 6];
            if (idx + 7 < n) vb.w = deg[idx + 7];
        }
        int sa = va.x + va.y + va.z + va.w;
        int s = sa + vb.x + vb.y + vb.z + vb.w;
        int incl = wave_incl_scan(s, lane);
        if (lane == 63) wsum[wid] = incl;
        __syncthreads();
        if (wid == 0) {
            int t = (lane < 16) ? wsum[lane] : 0;
            int ti = wave_incl_scan(t, lane);
            if (lane < 16) wsum[lane] = ti - t;
        }
        __syncthreads();
        int base_t = carry + wsum[wid] + incl - s;
        if (idx + 7 < n) {
            int4 st;
            st.x = base_t;
            st.y = base_t + va.x;
            st.z = base_t + va.x + va.y;
            st.w = base_t + va.x + va.y + va.z;
            *(int4*)(rp + idx) = st;
            int b4 = base_t + sa;
            st.x = b4;
            st.y = b4 + vb.x;
            st.z = b4 + vb.x + vb.y;
            st.w = b4 + vb.x + vb.y + vb.z;
            *(int4*)(rp + idx + 4) = st;
        } else {
            int r = base_t;
            if (idx + 0 < n) rp[idx + 0] = r; r += va.x;
            if (idx + 1 < n) rp[idx + 1] = r; r += va.y;
            if (idx + 2 < n) rp[idx + 2] = r; r += va.z;
            if (idx + 3 < n) rp[idx + 3] = r; r += va.w;
            if (idx + 4 < n) rp[idx + 4] = r; r += vb.x;
            if (idx + 5 < n) rp[idx + 5] = r; r += vb.y;
            if (idx + 6 < n) rp[idx + 6] = r; r += vb.z;
            if (idx + 7 < n) rp[idx + 7] = r;
        }
        __syncthreads();
        if (tid == 1023) carry += wsum[15] + incl;
        __syncthreads();
    }
    if (tid == 0) rp[n] = carry;
}

// ---------------- atomic-free fill, 4 edges/thread ----------------
__global__ __launch_bounds__(256)
void fill_kernel(const int* __restrict__ src_m, const int* __restrict__ dst_m,
                 const int* __restrict__ src_b, const int* __restrict__ dst_b,
                 const float* __restrict__ edge_w,
                 const int* __restrict__ rp_m, const int* __restrict__ rp_b,
                 const int* __restrict__ rank_m, const int* __restrict__ rank_b,
                 const u32* __restrict__ histm, const u32* __restrict__ histd,
                 int* __restrict__ srcs_m, int2* __restrict__ edges_b, int E)
{
    const int EQ = E / 4;      // 150000 (E divisible by 4)
    int t = blockIdx.x * 256 + threadIdx.x;
    if (t < EQ) {
        int e0 = 4 * t;
        int4 s4 = *(const int4*)(src_m + e0);
        int4 d4 = *(const int4*)(dst_m + e0);
        int4 r4 = *(const int4*)(rank_m + e0);
        int dd[4] = { d4.x, d4.y, d4.z, d4.w };
        int ss[4] = { s4.x, s4.y, s4.z, s4.w };
        int rr[4] = { r4.x, r4.y, r4.z, r4.w };
#pragma unroll
        for (int k = 0; k < 4; ++k) {
            int e = e0 + k, d = dd[k];
            int c = e / CHM;
            u32 pk = histm[(size_t)c * NWM8 + (d >> 2)];
            int base = (pk >> ((d & 3) * 8)) & 0xffu;
            srcs_m[rp_m[d] + base + rr[k]] = ss[k];
        }
    } else if (t < 2 * EQ) {
        int e0 = 4 * (t - EQ);
        int4 s4 = *(const int4*)(src_b + e0);
        int4 d4 = *(const int4*)(dst_b + e0);
        int4 r4 = *(const int4*)(rank_b + e0);
        float4 w4 = *(const float4*)(edge_w + e0);
        int dd[4] = { d4.x, d4.y, d4.z, d4.w };
        int ss[4] = { s4.x, s4.y, s4.z, s4.w };
        int rr[4] = { r4.x, r4.y, r4.z, r4.w };
        float ww[4] = { w4.x, w4.y, w4.z, w4.w };
#pragma unroll
        for (int k = 0; k < 4; ++k) {
            int e = e0 + k, d = dd[k];
            int c = e / CHM;
            u32 pkb = histd[(size_t)c * NWD8 + (d >> 2)];
            int base = (pkb >> ((d & 3) * 8)) & 0xffu;
            int pos = rp_b[d] + base + rr[k];
            int2 pk;
            pk.x = ss[k];
            pk.y = __float_as_int(1.0f / (1.0f + __expf(-ww[k])));
            edges_b[pos] = pk;
        }
    }
}

// ---------------- merged gather1+2, 32-lane groups, 8-deep ----------------
__global__ __launch_bounds__(256)
void gather12(const u16* __restrict__ Xb,
              const int* __restrict__ srcs_m, const int2* __restrict__ edges_b,
              const int* __restrict__ rp_m, const int* __restrict__ rp_b,
              u16* __restrict__ agg1, u16* __restrict__ agg2, int NM, int ND)
{
    const int h  = blockIdx.x * 8 + (threadIdx.x >> 5);
    const int cl = threadIdx.x & 31;
    float4 acc = make_float4(0.f, 0.f, 0.f, 0.f);

    if (h < NM) {
        int i   = rp_m[h];
        int end = rp_m[h + 1];
        for (; i + 8 <= end; i += 8) {
            int s0 = srcs_m[i+0], s1 = srcs_m[i+1], s2 = srcs_m[i+2], s3 = srcs_m[i+3];
            int s4 = srcs_m[i+4], s5 = srcs_m[i+5], s6 = srcs_m[i+6], s7 = srcs_m[i+7];
            ushort4 v0 = *(const ushort4*)(Xb + (size_t)s0 * 128 + cl * 4);
            ushort4 v1 = *(const ushort4*)(Xb + (size_t)s1 * 128 + cl * 4);
            ushort4 v2 = *(const ushort4*)(Xb + (size_t)s2 * 128 + cl * 4);
            ushort4 v3 = *(const ushort4*)(Xb + (size_t)s3 * 128 + cl * 4);
            ushort4 v4 = *(const ushort4*)(Xb + (size_t)s4 * 128 + cl * 4);
            ushort4 v5 = *(const ushort4*)(Xb + (size_t)s5 * 128 + cl * 4);
            ushort4 v6 = *(const ushort4*)(Xb + (size_t)s6 * 128 + cl * 4);
            ushort4 v7 = *(const ushort4*)(Xb + (size_t)s7 * 128 + cl * 4);
            acc.x += ((bf2f(v0.x)+bf2f(v1.x)) + (bf2f(v2.x)+bf2f(v3.x)))
                   + ((bf2f(v4.x)+bf2f(v5.x)) + (bf2f(v6.x)+bf2f(v7.x)));
            acc.y += ((bf2f(v0.y)+bf2f(v1.y)) + (bf2f(v2.y)+bf2f(v3.y)))
                   + ((bf2f(v4.y)+bf2f(v5.y)) + (bf2f(v6.y)+bf2f(v7.y)));
            acc.z += ((bf2f(v0.z)+bf2f(v1.z)) + (bf2f(v2.z)+bf2f(v3.z)))
                   + ((bf2f(v4.z)+bf2f(v5.z)) + (bf2f(v6.z)+bf2f(v7.z)));
            acc.w += ((bf2f(v0.w)+bf2f(v1.w)) + (bf2f(v2.w)+bf2f(v3.w)))
                   + ((bf2f(v4.w)+bf2f(v5.w)) + (bf2f(v6.w)+bf2f(v7.w)));
        }
        for (; i + 4 <= end; i += 4) {
            int s0 = srcs_m[i], s1 = srcs_m[i + 1], s2 = srcs_m[i + 2], s3 = srcs_m[i + 3];
            ushort4 v0 = *(const ushort4*)(Xb + (size_t)s0 * 128 + cl * 4);
            ushort4 v1 = *(const ushort4*)(Xb + (size_t)s1 * 128 + cl * 4);
            ushort4 v2 = *(const ushort4*)(Xb + (size_t)s2 * 128 + cl * 4);
            ushort4 v3 = *(const ushort4*)(Xb + (size_t)s3 * 128 + cl * 4);
            acc.x += (bf2f(v0.x) + bf2f(v1.x)) + (bf2f(v2.x) + bf2f(v3.x));
            acc.y += (bf2f(v0.y) + bf2f(v1.y)) + (bf2f(v2.y) + bf2f(v3.y));
            acc.z += (bf2f(v0.z) + bf2f(v1.z)) + (bf2f(v2.z) + bf2f(v3.z));
            acc.w += (bf2f(v0.w) + bf2f(v1.w)) + (bf2f(v2.w) + bf2f(v3.w));
        }
        for (; i < end; ++i) {
            int s = srcs_m[i];
            ushort4 v = *(const ushort4*)(Xb + (size_t)s * 128 + cl * 4);
            acc.x += bf2f(v.x); acc.y += bf2f(v.y);
            acc.z += bf2f(v.z); acc.w += bf2f(v.w);
        }
        ushort4 st;
        st.x = f2bf(acc.x); st.y = f2bf(acc.y);
        st.z = f2bf(acc.z); st.w = f2bf(acc.w);
        *(ushort4*)(agg1 + (size_t)h * 128 + cl * 4) = st;
    } else if (h < NM + ND) {
        int node = h - NM;
        int i   = rp_b[node];
        int end = rp_b[node + 1];
        for (; i + 8 <= end; i += 8) {
            int2 p0 = edges_b[i+0], p1 = edges_b[i+1], p2 = edges_b[i+2], p3 = edges_b[i+3];
            int2 p4 = edges_b[i+4], p5 = edges_b[i+5], p6 = edges_b[i+6], p7 = edges_b[i+7];
            ushort4 v0 = *(const ushort4*)(Xb + (size_t)p0.x * 128 + cl * 4);
            ushort4 v1 = *(const ushort4*)(Xb + (size_t)p1.x * 128 + cl * 4);
            ushort4 v2 = *(const ushort4*)(Xb + (size_t)p2.x * 128 + cl * 4);
            ushort4 v3 = *(const ushort4*)(Xb + (size_t)p3.x * 128 + cl * 4);
            ushort4 v4 = *(const ushort4*)(Xb + (size_t)p4.x * 128 + cl * 4);
            ushort4 v5 = *(const ushort4*)(Xb + (size_t)p5.x * 128 + cl * 4);
            ushort4 v6 = *(const ushort4*)(Xb + (size_t)p6.x * 128 + cl * 4);
            ushort4 v7 = *(const ushort4*)(Xb + (size_t)p7.x * 128 + cl * 4);
            float w0 = __int_as_float(p0.y), w1 = __int_as_float(p1.y);
            float w2 = __int_as_float(p2.y), w3 = __int_as_float(p3.y);
            float w4 = __int_as_float(p4.y), w5 = __int_as_float(p5.y);
            float w6 = __int_as_float(p6.y), w7 = __int_as_float(p7.y);
            acc.x = fmaf(w0, bf2f(v0.x), acc.x); acc.y = fmaf(w0, bf2f(v0.y), acc.y);
            acc.z = fmaf(w0, bf2f(v0.z), acc.z); acc.w = fmaf(w0, bf2f(v0.w), acc.w);
            acc.x = fmaf(w1, bf2f(v1.x), acc.x); acc.y = fmaf(w1, bf2f(v1.y), acc.y);
            acc.z = fmaf(w1, bf2f(v1.z), acc.z); acc.w = fmaf(w1, bf2f(v1.w), acc.w);
            acc.x = fmaf(w2, bf2f(v2.x), acc.x); acc.y = fmaf(w2, bf2f(v2.y), acc.y);
            acc.z = fmaf(w2, bf2f(v2.z), acc.z); acc.w = fmaf(w2, bf2f(v2.w), acc.w);
            acc.x = fmaf(w3, bf2f(v3.x), acc.x); acc.y = fmaf(w3, bf2f(v3.y), acc.y);
            acc.z = fmaf(w3, bf2f(v3.z), acc.z); acc.w = fmaf(w3, bf2f(v3.w), acc.w);
            acc.x = fmaf(w4, bf2f(v4.x), acc.x); acc.y = fmaf(w4, bf2f(v4.y), acc.y);
            acc.z = fmaf(w4, bf2f(v4.z), acc.z); acc.w = fmaf(w4, bf2f(v4.w), acc.w);
            acc.x = fmaf(w5, bf2f(v5.x), acc.x); acc.y = fmaf(w5, bf2f(v5.y), acc.y);
            acc.z = fmaf(w5, bf2f(v5.z), acc.z); acc.w = fmaf(w5, bf2f(v5.w), acc.w);
            acc.x = fmaf(w6, bf2f(v6.x), acc.x); acc.y = fmaf(w6, bf2f(v6.y), acc.y);
            acc.z = fmaf(w6, bf2f(v6.z), acc.z); acc.w = fmaf(w6, bf2f(v6.w), acc.w);
            acc.x = fmaf(w7, bf2f(v7.x), acc.x); acc.y = fmaf(w7, bf2f(v7.y), acc.y);
            acc.z = fmaf(w7, bf2f(v7.z), acc.z); acc.w = fmaf(w7, bf2f(v7.w), acc.w);
        }
        for (; i + 4 <= end; i += 4) {
            int2 p0 = edges_b[i],     p1 = edges_b[i + 1];
            int2 p2 = edges_b[i + 2], p3 = edges_b[i + 3];
            float w0 = __int_as_float(p0.y), w1 = __int_as_float(p1.y);
            float w2 = __int_as_float(p2.y), w3 = __int_as_float(p3.y);
            ushort4 v0 = *(const ushort4*)(Xb + (size_t)p0.x * 128 + cl * 4);
            ushort4 v1 = *(const ushort4*)(Xb + (size_t)p1.x * 128 + cl * 4);
            ushort4 v2 = *(const ushort4*)(Xb + (size_t)p2.x * 128 + cl * 4);
            ushort4 v3 = *(const ushort4*)(Xb + (size_t)p3.x * 128 + cl * 4);
            acc.x = fmaf(w0, bf2f(v0.x), acc.x); acc.y = fmaf(w0, bf2f(v0.y), acc.y);
            acc.z = fmaf(w0, bf2f(v0.z), acc.z); acc.w = fmaf(w0, bf2f(v0.w), acc.w);
            acc.x = fmaf(w1, bf2f(v1.x), acc.x); acc.y = fmaf(w1, bf2f(v1.y), acc.y);
            acc.z = fmaf(w1, bf2f(v1.z), acc.z); acc.w = fmaf(w1, bf2f(v1.w), acc.w);
            acc.x = fmaf(w2, bf2f(v2.x), acc.x); acc.y = fmaf(w2, bf2f(v2.y), acc.y);
            acc.z = fmaf(w2, bf2f(v2.z), acc.z); acc.w = fmaf(w2, bf2f(v2.w), acc.w);
            acc.x = fmaf(w3, bf2f(v3.x), acc.x); acc.y = fmaf(w3, bf2f(v3.y), acc.y);
            acc.z = fmaf(w3, bf2f(v3.z), acc.z); acc.w = fmaf(w3, bf2f(v3.w), acc.w);
        }
        for (; i < end; ++i) {
            int2 pk = edges_b[i];
            float w = __int_as_float(pk.y);
            ushort4 v = *(const ushort4*)(Xb + (size_t)pk.x * 128 + cl * 4);
            acc.x = fmaf(w, bf2f(v.x), acc.x); acc.y = fmaf(w, bf2f(v.y), acc.y);
            acc.z = fmaf(w, bf2f(v.z), acc.z); acc.w = fmaf(w, bf2f(v.w), acc.w);
        }
        ushort4 st;
        st.x = f2bf(acc.x); st.y = f2bf(acc.y);
        st.z = f2bf(acc.z); st.w = f2bf(acc.w);
        *(ushort4*)(agg2 + (size_t)node * 128 + cl * 4) = st;
    }
}

// ---------------- gather3: 32-lane groups, 8-deep, weighted ----------------
__global__ __launch_bounds__(256)
void gather3_kernel(const u16* __restrict__ Mv, const int2* __restrict__ edges_b,
                    const int* __restrict__ rp_b, u16* __restrict__ agg3, int ND)
{
    const int node = blockIdx.x * 8 + (threadIdx.x >> 5);
    if (node >= ND) return;
    const int cl = threadIdx.x & 31;
    int i   = rp_b[node];
    int end = rp_b[node + 1];

    float4 acc = make_float4(0.f, 0.f, 0.f, 0.f);
    for (; i + 8 <= end; i += 8) {
        int2 p0 = edges_b[i+0], p1 = edges_b[i+1], p2 = edges_b[i+2], p3 = edges_b[i+3];
        int2 p4 = edges_b[i+4], p5 = edges_b[i+5], p6 = edges_b[i+6], p7 = edges_b[i+7];
        ushort4 v0 = *(const ushort4*)(Mv + (size_t)p0.x * 128 + cl * 4);
        ushort4 v1 = *(const ushort4*)(Mv + (size_t)p1.x * 128 + cl * 4);
        ushort4 v2 = *(const ushort4*)(Mv + (size_t)p2.x * 128 + cl * 4);
        ushort4 v3 = *(const ushort4*)(Mv + (size_t)p3.x * 128 + cl * 4);
        ushort4 v4 = *(const ushort4*)(Mv + (size_t)p4.x * 128 + cl * 4);
        ushort4 v5 = *(const ushort4*)(Mv + (size_t)p5.x * 128 + cl * 4);
        ushort4 v6 = *(const ushort4*)(Mv + (size_t)p6.x * 128 + cl * 4);
        ushort4 v7 = *(const ushort4*)(Mv + (size_t)p7.x * 128 + cl * 4);
        float w0 = __int_as_float(p0.y), w1 = __int_as_float(p1.y);
        float w2 = __int_as_float(p2.y), w3 = __int_as_float(p3.y);
        float w4 = __int_as_float(p4.y), w5 = __int_as_float(p5.y);
        float w6 = __int_as_float(p6.y), w7 = __int_as_float(p7.y);
        acc.x = fmaf(w0, bf2f(v0.x), acc.x); acc.y = fmaf(w0, bf2f(v0.y), acc.y);
        acc.z = fmaf(w0, bf2f(v0.z), acc.z); acc.w = fmaf(w0, bf2f(v0.w), acc.w);
        acc.x = fmaf(w1, bf2f(v1.x), acc.x); acc.y = fmaf(w1, bf2f(v1.y), acc.y);
        acc.z = fmaf(w1, bf2f(v1.z), acc.z); acc.w = fmaf(w1, bf2f(v1.w), acc.w);
        acc.x = fmaf(w2, bf2f(v2.x), acc.x); acc.y = fmaf(w2, bf2f(v2.y), acc.y);
        acc.z = fmaf(w2, bf2f(v2.z), acc.z); acc.w = fmaf(w2, bf2f(v2.w), acc.w);
        acc.x = fmaf(w3, bf2f(v3.x), acc.x); acc.y = fmaf(w3, bf2f(v3.y), acc.y);
        acc.z = fmaf(w3, bf2f(v3.z), acc.z); acc.w = fmaf(w3, bf2f(v3.w), acc.w);
        acc.x = fmaf(w4, bf2f(v4.x), acc.x); acc.y = fmaf(w4, bf2f(v4.y), acc.y);
        acc.z = fmaf(w4, bf2f(v4.z), acc.z); acc.w = fmaf(w4, bf2f(v4.w), acc.w);
        acc.x = fmaf(w5, bf2f(v5.x), acc.x); acc.y = fmaf(w5, bf2f(v5.y), acc.y);
        acc.z = fmaf(w5, bf2f(v5.z), acc.z); acc.w = fmaf(w5, bf2f(v5.w), acc.w);
        acc.x = fmaf(w6, bf2f(v6.x), acc.x); acc.y = fmaf(w6, bf2f(v6.y), acc.y);
        acc.z = fmaf(w6, bf2f(v6.z), acc.z); acc.w = fmaf(w6, bf2f(v6.w), acc.w);
        acc.x = fmaf(w7, bf2f(v7.x), acc.x); acc.y = fmaf(w7, bf2f(v7.y), acc.y);
        acc.z = fmaf(w7, bf2f(v7.z), acc.z); acc.w = fmaf(w7, bf2f(v7.w), acc.w);
    }
    for (; i + 4 <= end; i += 4) {
        int2 p0 = edges_b[i],     p1 = edges_b[i + 1];
        int2 p2 = edges_b[i + 2], p3 = edges_b[i + 3];
        float w0 = __int_as_float(p0.y), w1 = __int_as_float(p1.y);
        float w2 = __int_as_float(p2.y), w3 = __int_as_float(p3.y);
        ushort4 v0 = *(const ushort4*)(Mv + (size_t)p0.x * 128 + cl * 4);
        ushort4 v1 = *(const ushort4*)(Mv + (size_t)p1.x * 128 + cl * 4);
        ushort4 v2 = *(const ushort4*)(Mv + (size_t)p2.x * 128 + cl * 4);
        ushort4 v3 = *(const ushort4*)(Mv + (size_t)p3.x * 128 + cl * 4);
        acc.x = fmaf(w0, bf2f(v0.x), acc.x); acc.y = fmaf(w0, bf2f(v0.y), acc.y);
        acc.z = fmaf(w0, bf2f(v0.z), acc.z); acc.w = fmaf(w0, bf2f(v0.w), acc.w);
        acc.x = fmaf(w1, bf2f(v1.x), acc.x); acc.y = fmaf(w1, bf2f(v1.y), acc.y);
        acc.z = fmaf(w1, bf2f(v1.z), acc.z); acc.w = fmaf(w1, bf2f(v1.w), acc.w);
        acc.x = fmaf(w2, bf2f(v2.x), acc.x); acc.y = fmaf(w2, bf2f(v2.y), acc.y);
        acc.z = fmaf(w2, bf2f(v2.z), acc.z); acc.w = fmaf(w2, bf2f(v2.w), acc.w);
        acc.x = fmaf(w3, bf2f(v3.x), acc.x); acc.y = fmaf(w3, bf2f(v3.y), acc.y);
        acc.z = fmaf(w3, bf2f(v3.z), acc.z); acc.w = fmaf(w3, bf2f(v3.w), acc.w);
    }
    for (; i < end; ++i) {
        int2 pk = edges_b[i];
        float w = __int_as_float(pk.y);
        ushort4 v = *(const ushort4*)(Mv + (size_t)pk.x * 128 + cl * 4);
        acc.x = fmaf(w, bf2f(v.x), acc.x); acc.y = fmaf(w, bf2f(v.y), acc.y);
        acc.z = fmaf(w, bf2f(v.z), acc.z); acc.w = fmaf(w, bf2f(v.w), acc.w);
    }
    ushort4 st;
    st.x = f2bf(acc.x); st.y = f2bf(acc.y);
    st.z = f2bf(acc.z); st.w = f2bf(acc.w);
    *(ushort4*)(agg3 + (size_t)node * 128 + cl * 4) = st;
}

// ------- merged MFMA conv1+conv2, LDS-free (W from L2 wbuf) -------
// Body verified correct by R21's passing run (pipeline P4).
__global__ __launch_bounds__(256)
void conv12_mfma(const u16* __restrict__ agg1, const u16* __restrict__ w1r,
                 const float* __restrict__ b1, const u16* __restrict__ xm_bf,
                 const u16* __restrict__ w1o, u16* __restrict__ C1, int N1, int cb1,
                 const u16* __restrict__ agg2, const u16* __restrict__ w2r,
                 const float* __restrict__ b2, const u16* __restrict__ xd_bf,
                 const u16* __restrict__ w2o, u16* __restrict__ C2, int N2)
{
    const bool seg1 = (int)blockIdx.x < cb1;
    const u16 *A0, *A1p, *Wr, *Wo; const float* bias; u16* C; int N, base;
    if (seg1) { A0 = agg1; A1p = xm_bf; Wr = w1r; Wo = w1o; bias = b1; C = C1; N = N1; base = blockIdx.x; }
    else      { A0 = agg2; A1p = xd_bf; Wr = w2r; Wo = w2o; bias = b2; C = C2; N = N2; base = blockIdx.x - cb1; }

    const int tid  = threadIdx.x;
    const int lane = tid & 63;
    const int m0   = (base * 4 + (tid >> 6)) * 32;
    const int lr   = lane & 15;
    const int quad = lane >> 4;

    int r0 = m0 + lr;      if (r0 >= N) r0 = N - 1;
    int r1 = m0 + 16 + lr; if (r1 >= N) r1 = N - 1;

    f32x4 acc[2][8];
#pragma unroll
    for (int mt = 0; mt < 2; ++mt)
#pragma unroll
        for (int n = 0; n < 8; ++n) acc[mt][n] = (f32x4){0.f, 0.f, 0.f, 0.f};

#pragma unroll
    for (int c = 0; c < 4; ++c) {
        const int kb = c * 32 + quad * 8;
        bf16x8 a0 = *(const bf16x8*)(A0 + (size_t)r0 * 128 + kb);
        bf16x8 a1 = *(const bf16x8*)(A0 + (size_t)r1 * 128 + kb);
        const u16* wp = Wr + c * 4096 + lane * 8;
#pragma unroll
        for (int n = 0; n < 8; ++n) {
            bf16x8 b = *(const bf16x8*)(wp + n * 512);
            acc[0][n] = __builtin_amdgcn_mfma_f32_16x16x32_bf16(a0, b, acc[0][n], 0, 0, 0);
            acc[1][n] = __builtin_amdgcn_mfma_f32_16x16x32_bf16(a1, b, acc[1][n], 0, 0, 0);
        }
    }
#pragma unroll
    for (int c = 0; c < 4; ++c) {
        const int kb = c * 32 + quad * 8;
        bf16x8 a0 = *(const bf16x8*)(A1p + (size_t)r0 * 128 + kb);
        bf16x8 a1 = *(const bf16x8*)(A1p + (size_t)r1 * 128 + kb);
        const u16* wp = Wo + c * 4096 + lane * 8;
#pragma unroll
        for (int n = 0; n < 8; ++n) {
            bf16x8 b = *(const bf16x8*)(wp + n * 512);
            acc[0][n] = __builtin_amdgcn_mfma_f32_16x16x32_bf16(a0, b, acc[0][n], 0, 0, 0);
            acc[1][n] = __builtin_amdgcn_mfma_f32_16x16x32_bf16(a1, b, acc[1][n], 0, 0, 0);
        }
    }

#pragma unroll
    for (int mt = 0; mt < 2; ++mt) {
#pragma unroll
        for (int n = 0; n < 8; ++n) {
            const int col = n * 16 + lr;
            const float b = bias[col];
#pragma unroll
            for (int r = 0; r < 4; ++r) {
                int row = m0 + mt * 16 + quad * 4 + r;
                if (row >= N) continue;
                C[(size_t)row * 128 + col] = f2bf(fmaxf(acc[mt][n][r] + b, 0.f));
            }
        }
    }
}

// ---------------- conv3 + lin fused (bf16 A), 50 KB LDS ----------------
__global__ __launch_bounds__(256)
void conv3_lin(const u16* __restrict__ A1, const u16* __restrict__ Wr,
               const float* __restrict__ bias3,
               const u16* __restrict__ A2, const u16* __restrict__ Wo,
               const u16* __restrict__ Wl, const float* __restrict__ bias_l,
               float* __restrict__ out, int N)
{
    __shared__ u16 lds[17408 + 8192];   // 34 KB tile region + 16 KB lin W
    u16* tile = lds;
    u16* sWl  = lds + 17408;

    const int tid  = threadIdx.x;
    const int lane = tid & 63;
    const int wv   = tid >> 6;
    const int wbase = wv * 32;
    const int m0   = (blockIdx.x * 4 + wv) * 32;
    const int lr   = lane & 15;
    const int quad = lane >> 4;

    int r0 = m0 + lr;      if (r0 >= N) r0 = N - 1;
    int r1 = m0 + 16 + lr; if (r1 >= N) r1 = N - 1;

    f32x4 acc[2][8];
#pragma unroll
    for (int mt = 0; mt < 2; ++mt)
#pragma unroll
        for (int n = 0; n < 8; ++n) acc[mt][n] = (f32x4){0.f, 0.f, 0.f, 0.f};

    for (int i = tid; i < 1024; i += 256)
        ((uint4*)sWl)[i] = ((const uint4*)Wl)[i];
    for (int i = tid; i < 2048; i += 256)
        ((uint4*)lds)[i] = ((const uint4*)Wr)[i];
    __syncthreads();
#pragma unroll
    for (int c = 0; c < 4; ++c) {
        const int kb = c * 32 + quad * 8;
        bf16x8 a0 = *(const bf16x8*)(A1 + (size_t)r0 * 128 + kb);
        bf16x8 a1 = *(const bf16x8*)(A1 + (size_t)r1 * 128 + kb);
        const u16* wp = lds + c * 4096 + lane * 8;
#pragma unroll
        for (int n = 0; n < 8; ++n) {
            bf16x8 b = *(const bf16x8*)(wp + n * 512);
            acc[0][n] = __builtin_amdgcn_mfma_f32_16x16x32_bf16(a0, b, acc[0][n], 0, 0, 0);
            acc[1][n] = __builtin_amdgcn_mfma_f32_16x16x32_bf16(a1, b, acc[1][n], 0, 0, 0);
        }
    }
    __syncthreads();
    for (int i = tid; i < 2048; i += 256)
        ((uint4*)lds)[i] = ((const uint4*)Wo)[i];
    __syncthreads();
#pragma unroll
    for (int c = 0; c < 4; ++c) {
        const int kb = c * 32 + quad * 8;
        bf16x8 a0 = *(const bf16x8*)(A2 + (size_t)r0 * 128 + kb);
        bf16x8 a1 = *(const bf16x8*)(A2 + (size_t)r1 * 128 + kb);
        const u16* wp = lds + c * 4096 + lane * 8;
#pragma unroll
        for (int n = 0; n < 8; ++n) {
            bf16x8 b = *(const bf16x8*)(wp + n * 512);
            acc[0][n] = __builtin_amdgcn_mfma_f32_16x16x32_bf16(a0, b, acc[0][n], 0, 0, 0);
            acc[1][n] = __builtin_amdgcn_mfma_f32_16x16x32_bf16(a1, b, acc[1][n], 0, 0, 0);
        }
    }
    __syncthreads();   // done reading conv W; tile overlays it

#pragma unroll
    for (int mt = 0; mt < 2; ++mt) {
#pragma unroll
        for (int n = 0; n < 8; ++n) {
            const int col = n * 16 + lr;
            const float b = bias3[col];
#pragma unroll
            for (int r = 0; r < 4; ++r) {
                int row = wbase + mt * 16 + quad * 4 + r;
                tile[row * 136 + col] = f2bf(fmaxf(acc[mt][n][r] + b, 0.f));
            }
        }
    }
    __syncthreads();

    f32x4 acc2[2][4];
#pragma unroll
    for (int mt = 0; mt < 2; ++mt)
#pragma unroll
        for (int n = 0; n < 4; ++n) acc2[mt][n] = (f32x4){0.f, 0.f, 0.f, 0.f};

#pragma unroll
    for (int c = 0; c < 4; ++c) {
        const int kb = c * 32 + quad * 8;
        bf16x8 a0 = *(const bf16x8*)(tile + (wbase + lr) * 136 + kb);
        bf16x8 a1 = *(const bf16x8*)(tile + (wbase + 16 + lr) * 136 + kb);
#pragma unroll
        for (int n = 0; n < 4; ++n) {
            bf16x8 b = *(const bf16x8*)(sWl + c * 2048 + n * 512 + lane * 8);
            acc2[0][n] = __builtin_amdgcn_mfma_f32_16x16x32_bf16(a0, b, acc2[0][n], 0, 0, 0);
            acc2[1][n] = __builtin_amdgcn_mfma_f32_16x16x32_bf16(a1, b, acc2[1][n], 0, 0, 0);
        }
    }

#pragma unroll
    for (int mt = 0; mt < 2; ++mt) {
#pragma unroll
        for (int n = 0; n < 4; ++n) {
            const int col = n * 16 + lr;
            const float b = bias_l[col];
#pragma unroll
            for (int r = 0; r < 4; ++r) {
                int row = m0 + mt * 16 + quad * 4 + r;
                if (row >= N) continue;
                out[(size_t)row * 64 + col] = acc2[mt][n][r] + b;
            }
        }
    }
}

extern "C" void kernel_launch(void* const* d_in, const int* in_sizes, int n_in,
                              void* d_out, int out_size, void* d_ws, size_t ws_size,
                              hipStream_t stream)
{
    const float* x_meas  = (const float*)d_in[0];
    const float* x_dem   = (const float*)d_in[1];
    const int*   src_m   = (const int*)d_in[2];
    const int*   dst_m   = (const int*)d_in[3];
    const int*   src_b   = (const int*)d_in[4];
    const int*   dst_b   = (const int*)d_in[5];
    const float* edge_w  = (const float*)d_in[6];
    const float* W_rel1  = (const float*)d_in[7];
    const float* b_rel1  = (const float*)d_in[8];
    const float* W_root1 = (const float*)d_in[9];
    const float* W_rel2  = (const float*)d_in[10];
    const float* b_rel2  = (const float*)d_in[11];
    const float* W_root2 = (const float*)d_in[12];
    const float* W_rel3  = (const float*)d_in[13];
    const float* b_rel3  = (const float*)d_in[14];
    const float* W_root3 = (const float*)d_in[15];
    const float* W_lin   = (const float*)d_in[16];
    const float* b_lin   = (const float*)d_in[17];
    float* out = (float*)d_out;

    const int NM = NMC, ND = NDC, E = EC;

    char* p = (char*)d_ws;
    auto alloc = [&](size_t bytes) { char* r = p; p += (bytes + 511) & ~(size_t)511; return r; };
    u32*   histm   = (u32*)alloc((size_t)CM * NWM8 * 4);  // 6.4 MB
    u32*   histd   = (u32*)alloc((size_t)CM * NWD8 * 4);  // 2.56 MB
    int*   deg_m   = (int*)alloc((size_t)NM * 4);
    int*   deg_b   = (int*)alloc((size_t)ND * 4);
    int*   rp_m    = (int*)alloc((size_t)(NM + 1) * 4);
    int*   rp_b    = (int*)alloc((size_t)(ND + 1) * 4);
    int*   srcs_m  = (int*)alloc((size_t)E * 4);
    int2*  edges_b = (int2*)alloc((size_t)E * 8);
    u16*   agg1    = (u16*)alloc((size_t)NM * 128 * 2);   // 12.8 MB bf16
    u16*   agg2    = (u16*)alloc((size_t)ND * 128 * 2);   // 5.12 MB
    u16*   movie   = (u16*)alloc((size_t)NM * 128 * 2);   // 12.8 MB (= xm_bf alias)
    u16*   t2      = (u16*)alloc((size_t)ND * 128 * 2);   // 5.12 MB
    u16*   xd_bf   = (u16*)alloc((size_t)ND * 128 * 2);   // 5.12 MB
    u16*   wbuf    = (u16*)alloc(7 * 16384 * 2);          // 224 KB
    // aliases (stream-serial lifetimes):
    int* rank_m = (int*)agg1;          // dies at fill; agg1 written by gather12
    int* rank_b = rank_m + E;          // 4.8 MB total <= 12.8 MB
    u16* xm_bf  = movie;               // conv1 reads own rows, writes own rows (safe)
    u16* agg3   = agg1;                // agg1 dead after conv12

    const int TB  = (NM * 16 + 255) / 256;     // 3125
    const int TB2 = (ND * 16 + 255) / 256;     // 1250
    const int WB  = 448;

    prep_hist<<<2 * CM + TB + TB2 + WB, 256, 0, stream>>>(
        dst_m, dst_b, rank_m, rank_b, histm, histd,
        x_meas, xm_bf, NM * 16, x_dem, xd_bf, ND * 16,
        W_rel1, W_root1, W_rel2, W_root2, W_rel3, W_root3, W_lin, wbuf,
        TB, TB2);

    basescan8<<<((NWM8 + NWD8) * 4 + 255) / 256, 256, 0, stream>>>(histm, histd, deg_m, deg_b);
    scan2_kernel<<<2, 1024, 0, stream>>>(deg_m, rp_m, NM, deg_b, rp_b, ND);

    const int FB = (2 * (E / 4) + 255) / 256;  // 1172
    fill_kernel<<<FB, 256, 0, stream>>>(src_m, dst_m, src_b, dst_b, edge_w,
                                        rp_m, rp_b, rank_m, rank_b,
                                        histm, histd, srcs_m, edges_b, E);

    gather12<<<(NM + ND + 7) / 8, 256, 0, stream>>>(xm_bf, srcs_m, edges_b,
                                                    rp_m, rp_b, agg1, agg2, NM, ND);

    const int cb1 = (NM + 127) / 128;
    const int cb2 = (ND + 127) / 128;
    u16* w1r = wbuf + 0 * 16384; u16* w1o = wbuf + 1 * 16384;
    u16* w2r = wbuf + 2 * 16384; u16* w2o = wbuf + 3 * 16384;
    u16* w3r = wbuf + 4 * 16384; u16* w3o = wbuf + 5 * 16384;
    u16* wl  = wbuf + 6 * 16384;
    conv12_mfma<<<cb1 + cb2, 256, 0, stream>>>(agg1, w1r, b_rel1, xm_bf, w1o, movie, NM, cb1,
                                               agg2, w2r, b_rel2, xd_bf, w2o, t2,    ND);

    gather3_kernel<<<(ND + 7) / 8, 256, 0, stream>>>(movie, edges_b, rp_b, agg3, ND);

    conv3_lin<<<cb2, 256, 0, stream>>>(agg3, w3r, b_rel3, t2, w3o, wl, b_lin, out, ND);
}